// Round 3
// baseline (121.615 us; speedup 1.0000x reference)
//
#include <hip/hip_runtime.h>

typedef _Float16 f16;
typedef _Float16 f16x8 __attribute__((ext_vector_type(8)));
typedef float f32x4 __attribute__((ext_vector_type(4)));

typedef __attribute__((address_space(1))) void gvoid;
typedef __attribute__((address_space(3))) void lvoid;
#define GLD16(gp, lp) __builtin_amdgcn_global_load_lds((gvoid*)(gp), (lvoid*)(lp), 16, 0, 0)

__device__ __forceinline__ f32x4 mfma16(f16x8 a, f16x8 b, f32x4 c) {
    return __builtin_amdgcn_mfma_f32_16x16x32_f16(a, b, c, 0, 0, 0);
}

// ---- weight transpose + f16 cast: in [512][C] f32 -> out [C][512] f16 (LDS tile) ----
__global__ __launch_bounds__(256) void k_wtrans(const float* __restrict__ in,
                                                f16* __restrict__ out, int C) {
    __shared__ float t[64][65];
    int tid = threadIdx.x;
    int c0 = blockIdx.x * 64, r0 = blockIdx.y * 64;
#pragma unroll
    for (int i = 0; i < 16; ++i) {
        int r = i * 4 + (tid >> 6), c = tid & 63;
        t[r][c] = in[(size_t)(r0 + r) * C + c0 + c];
    }
    __syncthreads();
#pragma unroll
    for (int i = 0; i < 16; ++i) {
        int cr = i * 4 + (tid >> 6), cc = tid & 63;
        out[(size_t)(c0 + cr) * 512 + r0 + cc] = (f16)t[cc][cr];
    }
}

// ---- LayerNorm: x [8192][512] f32 -> h [8192][512] f16 (1 wave/row) ----
__global__ __launch_bounds__(256) void k_ln(const float* __restrict__ x,
                                            const float* __restrict__ gamma,
                                            const float* __restrict__ beta,
                                            f16* __restrict__ h) {
    int row = blockIdx.x * 4 + (threadIdx.x >> 6);
    int lane = threadIdx.x & 63;
    const float* xr = x + (size_t)row * 512;
    float4 a = ((const float4*)xr)[lane * 2];
    float4 b = ((const float4*)xr)[lane * 2 + 1];
    float v[8] = {a.x, a.y, a.z, a.w, b.x, b.y, b.z, b.w};
    float s = 0.f, s2 = 0.f;
#pragma unroll
    for (int j = 0; j < 8; ++j) { s += v[j]; s2 += v[j] * v[j]; }
#pragma unroll
    for (int off = 1; off < 64; off <<= 1) {
        s  += __shfl_xor(s, off);
        s2 += __shfl_xor(s2, off);
    }
    float mu  = s * (1.f / 512.f);
    float var = s2 * (1.f / 512.f) - mu * mu;
    float rstd = rsqrtf(var + 1e-5f);
    float4 g0 = ((const float4*)gamma)[lane * 2];
    float4 g1 = ((const float4*)gamma)[lane * 2 + 1];
    float4 b0 = ((const float4*)beta)[lane * 2];
    float4 b1 = ((const float4*)beta)[lane * 2 + 1];
    float g[8]  = {g0.x, g0.y, g0.z, g0.w, g1.x, g1.y, g1.z, g1.w};
    float bb[8] = {b0.x, b0.y, b0.z, b0.w, b1.x, b1.y, b1.z, b1.w};
    f16x8 o;
#pragma unroll
    for (int j = 0; j < 8; ++j) o[j] = (f16)((v[j] - mu) * rstd * g[j] + bb[j]);
    *(f16x8*)&h[(size_t)row * 512 + lane * 8] = o;
}

// ---- QKV GEMM (128x128 tile, BK=64, global_load_lds, seg-skip) ----
__global__ __launch_bounds__(256) void k_gemm_qkv(
    const f16* __restrict__ A, const f16* __restrict__ Bt, const int* __restrict__ mlab,
    f16* __restrict__ q, f16* __restrict__ kmat, f16* __restrict__ vt)
{
    __shared__ f16 As[128 * 64];
    __shared__ f16 Bs[128 * 64];
    int tid = threadIdx.x, wid = tid >> 6, lane = tid & 63;
    int wm = wid >> 1, wn = wid & 1;
    int l15 = lane & 15, l4 = lane >> 4;
    int rowBase = blockIdx.y * 128;
    int colBase = blockIdx.x * 128;
    int bb = rowBase >> 10, seg = (rowBase & 1023) >> 8;
    if (mlab[bb * 4 + seg] == 0) return;

    int srow = lane >> 3;
    int scol = (lane & 7) * 8;
    f32x4 acc[4][4] = {};
    for (int kt = 0; kt < 512; kt += 64) {
#pragma unroll
        for (int i = 0; i < 4; ++i) {
            int rg = (wid * 4 + i) * 8;
            GLD16(&A [(size_t)(rowBase + rg + srow) * 512 + kt + scol], &As[rg * 64]);
            GLD16(&Bt[(size_t)(colBase + rg + srow) * 512 + kt + scol], &Bs[rg * 64]);
        }
        __syncthreads();
#pragma unroll
        for (int kk = 0; kk < 2; ++kk) {
            f16x8 af[4], bf[4];
#pragma unroll
            for (int m = 0; m < 4; ++m) af[m] = *(const f16x8*)&As[(wm * 64 + m * 16 + l15) * 64 + kk * 32 + l4 * 8];
#pragma unroll
            for (int n = 0; n < 4; ++n) bf[n] = *(const f16x8*)&Bs[(wn * 64 + n * 16 + l15) * 64 + kk * 32 + l4 * 8];
#pragma unroll
            for (int m = 0; m < 4; ++m)
#pragma unroll
                for (int n = 0; n < 4; ++n)
                    acc[m][n] = mfma16(af[m], bf[n], acc[m][n]);
        }
        __syncthreads();
    }
#pragma unroll
    for (int m = 0; m < 4; ++m)
#pragma unroll
        for (int n = 0; n < 4; ++n)
#pragma unroll
            for (int r = 0; r < 4; ++r) {
                int row = rowBase + wm * 64 + m * 16 + l4 * 4 + r;
                int col = colBase + wn * 64 + n * 16 + l15;
                f16 hv = (f16)acc[m][n][r];
                int b = row >> 10, nt = row & 1023;
                int which = col >> 9, hh = (col >> 6) & 7, d = col & 63;
                size_t hidx = ((size_t)(b * 8 + hh) * 1024 + nt) * 64 + d;
                if (which == 0)      q[hidx] = hv;
                else if (which == 1) kmat[hidx] = hv;
                else                 vt[((size_t)(b * 8 + hh) * 64 + d) * 1024 + nt] = hv;
            }
}

// ---- masked flash attention v3: LDS-free, barrier-free, XCD-swizzled ----
// 1024 blocks; decode keeps all 16 q-blocks of one (b,h) on one XCD.
__global__ __launch_bounds__(256, 4) void k_attn(
    const f16* __restrict__ q, const f16* __restrict__ kmat,
    const f16* __restrict__ vt, const int* __restrict__ mlab,
    f16* __restrict__ ao)
{
    int bid = blockIdx.x;
    int bh = (bid & 7) + 8 * (bid >> 7);      // XCD = bid%8 -> fixed per bh
    int qb = (bid >> 3) & 15;
    int b = bh >> 3, hh = bh & 7;
    int tid = threadIdx.x, wid = tid >> 6, lane = tid & 63;
    int l15 = lane & 15, l4 = lane >> 4;
    int qbase = qb * 64;
    size_t bhs = (size_t)bh;

    if (mlab[b * 4 + (qb >> 2)] == 0) {       // missing q-segment -> exact zeros
        f16x8 z = {};
#pragma unroll
        for (int i = 0; i < 2; ++i) {
            int idx = tid + i * 256;
            *(f16x8*)&ao[(size_t)(b * 1024 + qbase + (idx >> 3)) * 512 + hh * 64 + (idx & 7) * 8] = z;
        }
        return;
    }

    // present 128-token chunks, packed 4 bits each (value = t0/128)
    unsigned chpack = 0; int nch = 0;
#pragma unroll
    for (int s = 0; s < 4; ++s)
        if (mlab[b * 4 + s] != 0) {
            chpack |= (unsigned)(2 * s)     << (4 * nch); ++nch;
            chpack |= (unsigned)(2 * s + 1) << (4 * nch); ++nch;
        }

    // Q fragment (B-operand rows = this wave's 16 q rows), pre-scaled by 1/8
    f16x8 qf[2];
#pragma unroll
    for (int kk = 0; kk < 2; ++kk) {
        qf[kk] = *(const f16x8*)&q[(bhs * 1024 + qbase + wid * 16 + l15) * 64 + kk * 32 + l4 * 8];
#pragma unroll
        for (int j = 0; j < 8; ++j) qf[kk][j] = qf[kk][j] * (f16)0.125;
    }

    float mrun = -1e30f, lrun = 0.f;
    f32x4 o[4] = {};

    const f16* kbase = kmat + bhs * 1024 * 64 + (size_t)(l15 * 64 + l4 * 8);
    const f16* vbase = vt + bhs * 64 * 1024 + (size_t)(l15 * 1024 + l4 * 8);

    for (int c = 0; c < nch; ++c) {
        int t0 = (int)((chpack >> (4 * c)) & 15) << 7;

        // QK^T swapped: read K fragments straight from L2
        f16x8 ka[2][8];
#pragma unroll
        for (int kk = 0; kk < 2; ++kk)
#pragma unroll
            for (int n = 0; n < 8; ++n)
                ka[kk][n] = *(const f16x8*)&kbase[(size_t)(t0 + n * 16) * 64 + kk * 32];
        f32x4 st[8] = {};
#pragma unroll
        for (int kk = 0; kk < 2; ++kk)
#pragma unroll
            for (int n = 0; n < 8; ++n)
                st[n] = mfma16(ka[kk][n], qf[kk], st[n]);

        // lane-local online softmax over this lane's 32 k-values
        f32x4 m4 = st[0];
#pragma unroll
        for (int n = 1; n < 8; ++n)
#pragma unroll
            for (int r = 0; r < 4; ++r) m4[r] = fmaxf(m4[r], st[n][r]);
        float mx = fmaxf(fmaxf(m4[0], m4[1]), fmaxf(m4[2], m4[3]));
        mx = fmaxf(mx, __shfl_xor(mx, 16));
        mx = fmaxf(mx, __shfl_xor(mx, 32));
        float mnew = fmaxf(mrun, mx);
        float alpha = __expf(mrun - mnew);
        mrun = mnew;
        float rs = 0.f;
        union PK { f16 h[4]; long long ll; } pk[8];
#pragma unroll
        for (int n = 0; n < 8; ++n)
#pragma unroll
            for (int r = 0; r < 4; ++r) {
                float p = __expf(st[n][r] - mnew);
                rs += p;
                pk[n].h[r] = (f16)p;
            }
        rs += __shfl_xor(rs, 16);
        rs += __shfl_xor(rs, 32);
        lrun = lrun * alpha + rs;
#pragma unroll
        for (int nd = 0; nd < 4; ++nd) o[nd] *= alpha;

        // redistribute P among 4-lane group (l15 fixed): target needs k=ks*32+l4*8+j
        int srcA = l15 + ((l4 & 1) * 2) * 16;
        int srcB = srcA + 16;
        int sel = l4 >> 1;
#pragma unroll
        for (int ks = 0; ks < 4; ++ks) {
            long long A0 = __shfl(pk[ks * 2].ll,     srcA);
            long long A1 = __shfl(pk[ks * 2 + 1].ll, srcA);
            long long B0 = __shfl(pk[ks * 2].ll,     srcB);
            long long B1 = __shfl(pk[ks * 2 + 1].ll, srcB);
            union PB { long long ll[2]; f16x8 v; } pb;
            pb.ll[0] = sel ? A1 : A0;
            pb.ll[1] = sel ? B1 : B0;
#pragma unroll
            for (int nd = 0; nd < 4; ++nd) {     // PV swapped: O^T[d][q], V direct from L2
                f16x8 va = *(const f16x8*)&vbase[(size_t)(nd * 16) * 1024 + t0 + ks * 32];
                o[nd] = mfma16(va, pb.v, o[nd]);
            }
        }
    }

    float inv = 1.f / lrun;
    int qrow = qbase + wid * 16 + l15;
#pragma unroll
    for (int nd = 0; nd < 4; ++nd) {
        union { f16 h[4]; long long ll; } w;
#pragma unroll
        for (int r = 0; r < 4; ++r) w.h[r] = (f16)(o[nd][r] * inv);
        *(long long*)&ao[(size_t)(b * 1024 + qrow) * 512 + hh * 64 + nd * 16 + l4 * 4] = w.ll;
    }
}

// ---- out GEMM (64x128 tile, BK=64, global_load_lds, bias-fill for zero rows) ----
__global__ __launch_bounds__(256) void k_gemm_out(
    const f16* __restrict__ A, const f16* __restrict__ Bt, const int* __restrict__ mlab,
    const float* __restrict__ bias, float* __restrict__ out)
{
    __shared__ f16 As[64 * 64];
    __shared__ f16 Bs[128 * 64];
    int tid = threadIdx.x, wid = tid >> 6, lane = tid & 63;
    int wm = wid >> 1, wn = wid & 1;
    int l15 = lane & 15, l4 = lane >> 4;
    int rowBase = blockIdx.y * 64;
    int colBase = blockIdx.x * 128;
    int bb = rowBase >> 10, seg = (rowBase & 1023) >> 8;
    if (mlab[bb * 4 + seg] == 0) {
        for (int i = tid; i < 64 * 128; i += 256)
            out[(size_t)(rowBase + (i >> 7)) * 512 + colBase + (i & 127)] = bias[colBase + (i & 127)];
        return;
    }

    int srow = lane >> 3, scol = (lane & 7) * 8;
    f32x4 acc[2][4] = {};
    for (int kt = 0; kt < 512; kt += 64) {
#pragma unroll
        for (int i = 0; i < 2; ++i) {
            int rg = (wid * 2 + i) * 8;
            GLD16(&A[(size_t)(rowBase + rg + srow) * 512 + kt + scol], &As[rg * 64]);
        }
#pragma unroll
        for (int i = 0; i < 4; ++i) {
            int rg = (wid * 4 + i) * 8;
            GLD16(&Bt[(size_t)(colBase + rg + srow) * 512 + kt + scol], &Bs[rg * 64]);
        }
        __syncthreads();
#pragma unroll
        for (int kk = 0; kk < 2; ++kk) {
            f16x8 af[2], bf[4];
#pragma unroll
            for (int m = 0; m < 2; ++m) af[m] = *(const f16x8*)&As[(wm * 32 + m * 16 + l15) * 64 + kk * 32 + l4 * 8];
#pragma unroll
            for (int n = 0; n < 4; ++n) bf[n] = *(const f16x8*)&Bs[(wn * 64 + n * 16 + l15) * 64 + kk * 32 + l4 * 8];
#pragma unroll
            for (int m = 0; m < 2; ++m)
#pragma unroll
                for (int n = 0; n < 4; ++n)
                    acc[m][n] = mfma16(af[m], bf[n], acc[m][n]);
        }
        __syncthreads();
    }
#pragma unroll
    for (int m = 0; m < 2; ++m)
#pragma unroll
        for (int n = 0; n < 4; ++n)
#pragma unroll
            for (int r = 0; r < 4; ++r) {
                int row = rowBase + wm * 32 + m * 16 + l4 * 4 + r;
                int col = colBase + wn * 64 + n * 16 + l15;
                out[(size_t)row * 512 + col] = acc[m][n][r] + bias[col];
            }
}

extern "C" void kernel_launch(void* const* d_in, const int* in_sizes, int n_in,
                              void* d_out, int out_size, void* d_ws, size_t ws_size,
                              hipStream_t stream) {
    const float* x     = (const float*)d_in[0];
    const int*   mlab  = (const int*)d_in[1];
    const float* gamma = (const float*)d_in[2];
    const float* beta  = (const float*)d_in[3];
    const float* wqkv  = (const float*)d_in[4];
    const float* wout  = (const float*)d_in[5];
    const float* bout  = (const float*)d_in[6];
    float* out = (float*)d_out;

    f16* h     = (f16*)d_ws;                 // 8192*512
    f16* wqkvT = h + 8192 * 512;             // 1536*512
    f16* woutT = wqkvT + 1536 * 512;         // 512*512
    f16* q     = woutT + 512 * 512;          // [B*H][1024][64]
    f16* kmat  = q + 4 * 1024 * 1024;
    f16* vt    = kmat + 4 * 1024 * 1024;     // [B*H][64][1024]
    f16* ao    = h;                          // h dead after QKV GEMM -> reuse

    k_wtrans<<<dim3(24, 8), 256, 0, stream>>>(wqkv, wqkvT, 1536);
    k_wtrans<<<dim3(8, 8), 256, 0, stream>>>(wout, woutT, 512);
    k_ln<<<2048, 256, 0, stream>>>(x, gamma, beta, h);
    k_gemm_qkv<<<dim3(12, 64), 256, 0, stream>>>(h, wqkvT, mlab, q, kmat, vt);
    k_attn<<<1024, 256, 0, stream>>>(q, kmat, vt, mlab, ao);
    k_gemm_out<<<dim3(4, 128), 256, 0, stream>>>(ao, woutT, mlab, bout, out);
}

// Round 4
// 113.047 us; speedup vs baseline: 1.0758x; 1.0758x over previous
//
#include <hip/hip_runtime.h>

typedef _Float16 f16;
typedef _Float16 f16x8 __attribute__((ext_vector_type(8)));
typedef float f32x4 __attribute__((ext_vector_type(4)));

typedef __attribute__((address_space(1))) void gvoid;
typedef __attribute__((address_space(3))) void lvoid;
#define GLD16(gp, lp) __builtin_amdgcn_global_load_lds((gvoid*)(gp), (lvoid*)(lp), 16, 0, 0)

__device__ __forceinline__ f32x4 mfma16(f16x8 a, f16x8 b, f32x4 c) {
    return __builtin_amdgcn_mfma_f32_16x16x32_f16(a, b, c, 0, 0, 0);
}

// ---- weight transpose + f16 cast: in [512][C] f32 -> out [C][512] f16 (LDS tile) ----
__global__ __launch_bounds__(256) void k_wtrans(const float* __restrict__ in,
                                                f16* __restrict__ out, int C) {
    __shared__ float t[64][65];
    int tid = threadIdx.x;
    int c0 = blockIdx.x * 64, r0 = blockIdx.y * 64;
#pragma unroll
    for (int i = 0; i < 16; ++i) {
        int r = i * 4 + (tid >> 6), c = tid & 63;
        t[r][c] = in[(size_t)(r0 + r) * C + c0 + c];
    }
    __syncthreads();
#pragma unroll
    for (int i = 0; i < 16; ++i) {
        int cr = i * 4 + (tid >> 6), cc = tid & 63;
        out[(size_t)(c0 + cr) * 512 + r0 + cc] = (f16)t[cc][cr];
    }
}

// ---- LayerNorm: x [8192][512] f32 -> h [8192][512] f16 (1 wave/row, seg-skip) ----
__global__ __launch_bounds__(256) void k_ln(const float* __restrict__ x,
                                            const float* __restrict__ gamma,
                                            const float* __restrict__ beta,
                                            const int* __restrict__ mlab,
                                            f16* __restrict__ h) {
    int row = blockIdx.x * 4 + (threadIdx.x >> 6);
    int b = row >> 10, seg = (row >> 8) & 3;
    if (mlab[b * 4 + seg] == 0) return;   // h rows of missing segs never read
    int lane = threadIdx.x & 63;
    const float* xr = x + (size_t)row * 512;
    float4 a = ((const float4*)xr)[lane * 2];
    float4 bv = ((const float4*)xr)[lane * 2 + 1];
    float v[8] = {a.x, a.y, a.z, a.w, bv.x, bv.y, bv.z, bv.w};
    float s = 0.f, s2 = 0.f;
#pragma unroll
    for (int j = 0; j < 8; ++j) { s += v[j]; s2 += v[j] * v[j]; }
#pragma unroll
    for (int off = 1; off < 64; off <<= 1) {
        s  += __shfl_xor(s, off);
        s2 += __shfl_xor(s2, off);
    }
    float mu  = s * (1.f / 512.f);
    float var = s2 * (1.f / 512.f) - mu * mu;
    float rstd = rsqrtf(var + 1e-5f);
    float4 g0 = ((const float4*)gamma)[lane * 2];
    float4 g1 = ((const float4*)gamma)[lane * 2 + 1];
    float4 b0 = ((const float4*)beta)[lane * 2];
    float4 b1 = ((const float4*)beta)[lane * 2 + 1];
    float g[8]  = {g0.x, g0.y, g0.z, g0.w, g1.x, g1.y, g1.z, g1.w};
    float bb[8] = {b0.x, b0.y, b0.z, b0.w, b1.x, b1.y, b1.z, b1.w};
    f16x8 o;
#pragma unroll
    for (int j = 0; j < 8; ++j) o[j] = (f16)((v[j] - mu) * rstd * g[j] + bb[j]);
    *(f16x8*)&h[(size_t)row * 512 + lane * 8] = o;
}

// ---- QKV GEMM (128x128 tile, BK=64, global_load_lds, seg-skip) ----
__global__ __launch_bounds__(256) void k_gemm_qkv(
    const f16* __restrict__ A, const f16* __restrict__ Bt, const int* __restrict__ mlab,
    f16* __restrict__ q, f16* __restrict__ kmat, f16* __restrict__ vt)
{
    __shared__ f16 As[128 * 64];
    __shared__ f16 Bs[128 * 64];
    int tid = threadIdx.x, wid = tid >> 6, lane = tid & 63;
    int wm = wid >> 1, wn = wid & 1;
    int l15 = lane & 15, l4 = lane >> 4;
    int rowBase = blockIdx.y * 128;
    int colBase = blockIdx.x * 128;
    int bb = rowBase >> 10, seg = (rowBase & 1023) >> 8;
    if (mlab[bb * 4 + seg] == 0) return;

    int srow = lane >> 3;
    int scol = (lane & 7) * 8;
    f32x4 acc[4][4] = {};
    for (int kt = 0; kt < 512; kt += 64) {
#pragma unroll
        for (int i = 0; i < 4; ++i) {
            int rg = (wid * 4 + i) * 8;
            GLD16(&A [(size_t)(rowBase + rg + srow) * 512 + kt + scol], &As[rg * 64]);
            GLD16(&Bt[(size_t)(colBase + rg + srow) * 512 + kt + scol], &Bs[rg * 64]);
        }
        __syncthreads();
#pragma unroll
        for (int kk = 0; kk < 2; ++kk) {
            f16x8 af[4], bf[4];
#pragma unroll
            for (int m = 0; m < 4; ++m) af[m] = *(const f16x8*)&As[(wm * 64 + m * 16 + l15) * 64 + kk * 32 + l4 * 8];
#pragma unroll
            for (int n = 0; n < 4; ++n) bf[n] = *(const f16x8*)&Bs[(wn * 64 + n * 16 + l15) * 64 + kk * 32 + l4 * 8];
#pragma unroll
            for (int m = 0; m < 4; ++m)
#pragma unroll
                for (int n = 0; n < 4; ++n)
                    acc[m][n] = mfma16(af[m], bf[n], acc[m][n]);
        }
        __syncthreads();
    }
#pragma unroll
    for (int m = 0; m < 4; ++m)
#pragma unroll
        for (int n = 0; n < 4; ++n)
#pragma unroll
            for (int r = 0; r < 4; ++r) {
                int row = rowBase + wm * 64 + m * 16 + l4 * 4 + r;
                int col = colBase + wn * 64 + n * 16 + l15;
                f16 hv = (f16)acc[m][n][r];
                int b = row >> 10, nt = row & 1023;
                int which = col >> 9, hh = (col >> 6) & 7, d = col & 63;
                size_t hidx = ((size_t)(b * 8 + hh) * 1024 + nt) * 64 + d;
                if (which == 0)      q[hidx] = hv;
                else if (which == 1) kmat[hidx] = hv;
                else                 vt[((size_t)(b * 8 + hh) * 64 + d) * 1024 + nt] = hv;
            }
}

// ---- masked flash attention v4: in-block split-K, batched K/V reg loads ----
// 1024 blocks x 512 threads. 8 waves: wave-group g = wid>>2 handles chunks
// c = g, g+2, ...; q-slice = wid&3 (16 rows). LDS only for the final merge.
__global__ __launch_bounds__(512, 4) void k_attn(
    const f16* __restrict__ q, const f16* __restrict__ kmat,
    const f16* __restrict__ vt, const int* __restrict__ mlab,
    f16* __restrict__ ao)
{
    __shared__ float So[4][64][18];
    __shared__ float Sm[4][16], Sl[4][16];

    int bid = blockIdx.x;
    int bh = (bid & 7) + 8 * (bid >> 7);      // all 16 q-blocks of a bh on one XCD
    int qb = (bid >> 3) & 15;
    int b = bh >> 3, hh = bh & 7;
    int tid = threadIdx.x, wid = tid >> 6, lane = tid & 63;
    int qs = wid & 3, g = wid >> 2;
    int l15 = lane & 15, l4 = lane >> 4;
    int qbase = qb * 64;
    size_t bhs = (size_t)bh;

    if (mlab[b * 4 + (qb >> 2)] == 0) return;  // out rows filled by k_gemm_out bias path

    unsigned chpack = 0; int nch = 0;
#pragma unroll
    for (int s = 0; s < 4; ++s)
        if (mlab[b * 4 + s] != 0) {
            chpack |= (unsigned)(2 * s)     << (4 * nch); ++nch;
            chpack |= (unsigned)(2 * s + 1) << (4 * nch); ++nch;
        }

    // Q fragment for this wave's 16 q rows, pre-scaled by 1/8
    f16x8 qf[2];
#pragma unroll
    for (int kk = 0; kk < 2; ++kk) {
        qf[kk] = *(const f16x8*)&q[(bhs * 1024 + qbase + qs * 16 + l15) * 64 + kk * 32 + l4 * 8];
#pragma unroll
        for (int j = 0; j < 8; ++j) qf[kk][j] = qf[kk][j] * (f16)0.125;
    }

    float mrun = -1e30f, lrun = 0.f;
    f32x4 o[4] = {};

    const f16* kbase = kmat + bhs * 1024 * 64 + (size_t)(l15 * 64 + l4 * 8);
    const f16* vbase = vt + bhs * 64 * 1024 + (size_t)(l15 * 1024 + l4 * 8);

    for (int c = g; c < nch; c += 2) {
        int t0 = (int)((chpack >> (4 * c)) & 15) << 7;

        // load ALL 16 K fragments (independent), then MFMA — one latency wait
        f16x8 ka[2][8];
#pragma unroll
        for (int kk = 0; kk < 2; ++kk)
#pragma unroll
            for (int n = 0; n < 8; ++n)
                ka[kk][n] = *(const f16x8*)&kbase[(size_t)(t0 + n * 16) * 64 + kk * 32];
        f32x4 st[8] = {};
#pragma unroll
        for (int kk = 0; kk < 2; ++kk)
#pragma unroll
            for (int n = 0; n < 8; ++n)
                st[n] = mfma16(ka[kk][n], qf[kk], st[n]);

        // V double-buffer: issue ks=0 loads before softmax (latency hidden under VALU)
        f16x8 va[4], vb[4];
#pragma unroll
        for (int nd = 0; nd < 4; ++nd)
            va[nd] = *(const f16x8*)&vbase[(size_t)(nd * 16) * 1024 + t0];

        // lane-local online softmax over this lane's 32 k-values
        f32x4 m4 = st[0];
#pragma unroll
        for (int n = 1; n < 8; ++n)
#pragma unroll
            for (int r = 0; r < 4; ++r) m4[r] = fmaxf(m4[r], st[n][r]);
        float mx = fmaxf(fmaxf(m4[0], m4[1]), fmaxf(m4[2], m4[3]));
        mx = fmaxf(mx, __shfl_xor(mx, 16));
        mx = fmaxf(mx, __shfl_xor(mx, 32));
        float mnew = fmaxf(mrun, mx);
        float alpha = __expf(mrun - mnew);
        mrun = mnew;
        float rs = 0.f;
        union PK { f16 h[4]; long long ll; } pk[8];
#pragma unroll
        for (int n = 0; n < 8; ++n)
#pragma unroll
            for (int r = 0; r < 4; ++r) {
                float p = __expf(st[n][r] - mnew);
                rs += p;
                pk[n].h[r] = (f16)p;
            }
        rs += __shfl_xor(rs, 16);
        rs += __shfl_xor(rs, 32);
        lrun = lrun * alpha + rs;
#pragma unroll
        for (int nd = 0; nd < 4; ++nd) o[nd] *= alpha;

        // P redistribution within 4-lane groups + PV (V prefetched one ks ahead)
        int srcA = l15 + ((l4 & 1) * 2) * 16;
        int srcB = srcA + 16;
        int sel = l4 >> 1;
#pragma unroll
        for (int ks = 0; ks < 4; ++ks) {
            if (ks < 3) {
#pragma unroll
                for (int nd = 0; nd < 4; ++nd)
                    vb[nd] = *(const f16x8*)&vbase[(size_t)(nd * 16) * 1024 + t0 + (ks + 1) * 32];
            }
            long long A0 = __shfl(pk[ks * 2].ll,     srcA);
            long long A1 = __shfl(pk[ks * 2 + 1].ll, srcA);
            long long B0 = __shfl(pk[ks * 2].ll,     srcB);
            long long B1 = __shfl(pk[ks * 2 + 1].ll, srcB);
            union PB { long long ll[2]; f16x8 v; } pb;
            pb.ll[0] = sel ? A1 : A0;
            pb.ll[1] = sel ? B1 : B0;
#pragma unroll
            for (int nd = 0; nd < 4; ++nd)
                o[nd] = mfma16(va[nd], pb.v, o[nd]);
#pragma unroll
            for (int nd = 0; nd < 4; ++nd) va[nd] = vb[nd];
        }
    }

    // ---- split-K merge: g=1 publishes partials, g=0 merges + writes ----
    if (g == 1) {
        if (l4 == 0) { Sm[qs][l15] = mrun; Sl[qs][l15] = lrun; }
#pragma unroll
        for (int nd = 0; nd < 4; ++nd)
#pragma unroll
            for (int r = 0; r < 4; ++r)
                So[qs][nd * 16 + l4 * 4 + r][l15] = o[nd][r];
    }
    __syncthreads();
    if (g == 0) {
        float m1 = Sm[qs][l15], l1 = Sl[qs][l15];
        float mst = fmaxf(mrun, m1);
        float e0 = __expf(mrun - mst), e1 = __expf(m1 - mst);
        float inv = 1.f / (lrun * e0 + l1 * e1);
        int qrow = qbase + qs * 16 + l15;
#pragma unroll
        for (int nd = 0; nd < 4; ++nd) {
            union { f16 h[4]; long long ll; } w;
#pragma unroll
            for (int r = 0; r < 4; ++r)
                w.h[r] = (f16)((o[nd][r] * e0 + So[qs][nd * 16 + l4 * 4 + r][l15] * e1) * inv);
            *(long long*)&ao[(size_t)(b * 1024 + qrow) * 512 + hh * 64 + nd * 16 + l4 * 4] = w.ll;
        }
    }
}

// ---- out GEMM (64x128 tile, BK=64, global_load_lds, bias-fill for zero rows) ----
__global__ __launch_bounds__(256) void k_gemm_out(
    const f16* __restrict__ A, const f16* __restrict__ Bt, const int* __restrict__ mlab,
    const float* __restrict__ bias, float* __restrict__ out)
{
    __shared__ f16 As[64 * 64];
    __shared__ f16 Bs[128 * 64];
    int tid = threadIdx.x, wid = tid >> 6, lane = tid & 63;
    int wm = wid >> 1, wn = wid & 1;
    int l15 = lane & 15, l4 = lane >> 4;
    int rowBase = blockIdx.y * 64;
    int colBase = blockIdx.x * 128;
    int bb = rowBase >> 10, seg = (rowBase & 1023) >> 8;
    if (mlab[bb * 4 + seg] == 0) {
        for (int i = tid; i < 64 * 128; i += 256)
            out[(size_t)(rowBase + (i >> 7)) * 512 + colBase + (i & 127)] = bias[colBase + (i & 127)];
        return;
    }

    int srow = lane >> 3, scol = (lane & 7) * 8;
    f32x4 acc[2][4] = {};
    for (int kt = 0; kt < 512; kt += 64) {
#pragma unroll
        for (int i = 0; i < 2; ++i) {
            int rg = (wid * 2 + i) * 8;
            GLD16(&A[(size_t)(rowBase + rg + srow) * 512 + kt + scol], &As[rg * 64]);
        }
#pragma unroll
        for (int i = 0; i < 4; ++i) {
            int rg = (wid * 4 + i) * 8;
            GLD16(&Bt[(size_t)(colBase + rg + srow) * 512 + kt + scol], &Bs[rg * 64]);
        }
        __syncthreads();
#pragma unroll
        for (int kk = 0; kk < 2; ++kk) {
            f16x8 af[2], bf[4];
#pragma unroll
            for (int m = 0; m < 2; ++m) af[m] = *(const f16x8*)&As[(wm * 32 + m * 16 + l15) * 64 + kk * 32 + l4 * 8];
#pragma unroll
            for (int n = 0; n < 4; ++n) bf[n] = *(const f16x8*)&Bs[(wn * 64 + n * 16 + l15) * 64 + kk * 32 + l4 * 8];
#pragma unroll
            for (int m = 0; m < 2; ++m)
#pragma unroll
                for (int n = 0; n < 4; ++n)
                    acc[m][n] = mfma16(af[m], bf[n], acc[m][n]);
        }
        __syncthreads();
    }
#pragma unroll
    for (int m = 0; m < 2; ++m)
#pragma unroll
        for (int n = 0; n < 4; ++n)
#pragma unroll
            for (int r = 0; r < 4; ++r) {
                int row = rowBase + wm * 32 + m * 16 + l4 * 4 + r;
                int col = colBase + wn * 64 + n * 16 + l15;
                out[(size_t)row * 512 + col] = acc[m][n][r] + bias[col];
            }
}

extern "C" void kernel_launch(void* const* d_in, const int* in_sizes, int n_in,
                              void* d_out, int out_size, void* d_ws, size_t ws_size,
                              hipStream_t stream) {
    const float* x     = (const float*)d_in[0];
    const int*   mlab  = (const int*)d_in[1];
    const float* gamma = (const float*)d_in[2];
    const float* beta  = (const float*)d_in[3];
    const float* wqkv  = (const float*)d_in[4];
    const float* wout  = (const float*)d_in[5];
    const float* bout  = (const float*)d_in[6];
    float* out = (float*)d_out;

    f16* h     = (f16*)d_ws;                 // 8192*512
    f16* wqkvT = h + 8192 * 512;             // 1536*512
    f16* woutT = wqkvT + 1536 * 512;         // 512*512
    f16* q     = woutT + 512 * 512;          // [B*H][1024][64]
    f16* kmat  = q + 4 * 1024 * 1024;
    f16* vt    = kmat + 4 * 1024 * 1024;     // [B*H][64][1024]
    f16* ao    = h;                          // h dead after QKV GEMM -> reuse

    k_wtrans<<<dim3(24, 8), 256, 0, stream>>>(wqkv, wqkvT, 1536);
    k_wtrans<<<dim3(8, 8), 256, 0, stream>>>(wout, woutT, 512);
    k_ln<<<2048, 256, 0, stream>>>(x, gamma, beta, mlab, h);
    k_gemm_qkv<<<dim3(12, 64), 256, 0, stream>>>(h, wqkvT, mlab, q, kmat, vt);
    k_attn<<<1024, 512, 0, stream>>>(q, kmat, vt, mlab, ao);
    k_gemm_out<<<dim3(4, 128), 256, 0, stream>>>(ao, woutT, mlab, bout, out);
}

// Round 5
// 85.440 us; speedup vs baseline: 1.4234x; 1.3231x over previous
//
#include <hip/hip_runtime.h>

typedef _Float16 f16;
typedef _Float16 f16x8 __attribute__((ext_vector_type(8)));
typedef float f32x4 __attribute__((ext_vector_type(4)));

typedef __attribute__((address_space(1))) void gvoid;
typedef __attribute__((address_space(3))) void lvoid;
#define GLD16(gp, lp) __builtin_amdgcn_global_load_lds((gvoid*)(gp), (lvoid*)(lp), 16, 0, 0)

__device__ __forceinline__ f32x4 mfma16(f16x8 a, f16x8 b, f32x4 c) {
    return __builtin_amdgcn_mfma_f32_16x16x32_f16(a, b, c, 0, 0, 0);
}

// ---- weight transpose + f16 cast: in [512][C] f32 -> out [C][512] f16 (LDS tile) ----
__global__ __launch_bounds__(256) void k_wtrans(const float* __restrict__ in,
                                                f16* __restrict__ out, int C) {
    __shared__ float t[64][65];
    int tid = threadIdx.x;
    int c0 = blockIdx.x * 64, r0 = blockIdx.y * 64;
#pragma unroll
    for (int i = 0; i < 16; ++i) {
        int r = i * 4 + (tid >> 6), c = tid & 63;
        t[r][c] = in[(size_t)(r0 + r) * C + c0 + c];
    }
    __syncthreads();
#pragma unroll
    for (int i = 0; i < 16; ++i) {
        int cr = i * 4 + (tid >> 6), cc = tid & 63;
        out[(size_t)(c0 + cr) * 512 + r0 + cc] = (f16)t[cc][cr];
    }
}

// ---- LayerNorm: x [8192][512] f32 -> h [8192][512] f16 (1 wave/row, seg-skip) ----
__global__ __launch_bounds__(256) void k_ln(const float* __restrict__ x,
                                            const float* __restrict__ gamma,
                                            const float* __restrict__ beta,
                                            const int* __restrict__ mlab,
                                            f16* __restrict__ h) {
    int row = blockIdx.x * 4 + (threadIdx.x >> 6);
    int b = row >> 10, seg = (row >> 8) & 3;
    if (mlab[b * 4 + seg] == 0) return;
    int lane = threadIdx.x & 63;
    const float* xr = x + (size_t)row * 512;
    float4 a = ((const float4*)xr)[lane * 2];
    float4 bv = ((const float4*)xr)[lane * 2 + 1];
    float v[8] = {a.x, a.y, a.z, a.w, bv.x, bv.y, bv.z, bv.w};
    float s = 0.f, s2 = 0.f;
#pragma unroll
    for (int j = 0; j < 8; ++j) { s += v[j]; s2 += v[j] * v[j]; }
#pragma unroll
    for (int off = 1; off < 64; off <<= 1) {
        s  += __shfl_xor(s, off);
        s2 += __shfl_xor(s2, off);
    }
    float mu  = s * (1.f / 512.f);
    float var = s2 * (1.f / 512.f) - mu * mu;
    float rstd = rsqrtf(var + 1e-5f);
    float4 g0 = ((const float4*)gamma)[lane * 2];
    float4 g1 = ((const float4*)gamma)[lane * 2 + 1];
    float4 b0 = ((const float4*)beta)[lane * 2];
    float4 b1 = ((const float4*)beta)[lane * 2 + 1];
    float g[8]  = {g0.x, g0.y, g0.z, g0.w, g1.x, g1.y, g1.z, g1.w};
    float bb[8] = {b0.x, b0.y, b0.z, b0.w, b1.x, b1.y, b1.z, b1.w};
    f16x8 o;
#pragma unroll
    for (int j = 0; j < 8; ++j) o[j] = (f16)((v[j] - mu) * rstd * g[j] + bb[j]);
    *(f16x8*)&h[(size_t)row * 512 + lane * 8] = o;
}

// ---- QKV GEMM (128x128 tile, BK=64, global_load_lds, seg-skip) ----
__global__ __launch_bounds__(256) void k_gemm_qkv(
    const f16* __restrict__ A, const f16* __restrict__ Bt, const int* __restrict__ mlab,
    f16* __restrict__ q, f16* __restrict__ kmat, f16* __restrict__ vt)
{
    __shared__ f16 As[128 * 64];
    __shared__ f16 Bs[128 * 64];
    int tid = threadIdx.x, wid = tid >> 6, lane = tid & 63;
    int wm = wid >> 1, wn = wid & 1;
    int l15 = lane & 15, l4 = lane >> 4;
    int rowBase = blockIdx.y * 128;
    int colBase = blockIdx.x * 128;
    int bb = rowBase >> 10, seg = (rowBase & 1023) >> 8;
    if (mlab[bb * 4 + seg] == 0) return;

    int srow = lane >> 3;
    int scol = (lane & 7) * 8;
    f32x4 acc[4][4] = {};
    for (int kt = 0; kt < 512; kt += 64) {
#pragma unroll
        for (int i = 0; i < 4; ++i) {
            int rg = (wid * 4 + i) * 8;
            GLD16(&A [(size_t)(rowBase + rg + srow) * 512 + kt + scol], &As[rg * 64]);
            GLD16(&Bt[(size_t)(colBase + rg + srow) * 512 + kt + scol], &Bs[rg * 64]);
        }
        __syncthreads();
#pragma unroll
        for (int kk = 0; kk < 2; ++kk) {
            f16x8 af[4], bf[4];
#pragma unroll
            for (int m = 0; m < 4; ++m) af[m] = *(const f16x8*)&As[(wm * 64 + m * 16 + l15) * 64 + kk * 32 + l4 * 8];
#pragma unroll
            for (int n = 0; n < 4; ++n) bf[n] = *(const f16x8*)&Bs[(wn * 64 + n * 16 + l15) * 64 + kk * 32 + l4 * 8];
#pragma unroll
            for (int m = 0; m < 4; ++m)
#pragma unroll
                for (int n = 0; n < 4; ++n)
                    acc[m][n] = mfma16(af[m], bf[n], acc[m][n]);
        }
        __syncthreads();
    }
#pragma unroll
    for (int m = 0; m < 4; ++m)
#pragma unroll
        for (int n = 0; n < 4; ++n)
#pragma unroll
            for (int r = 0; r < 4; ++r) {
                int row = rowBase + wm * 64 + m * 16 + l4 * 4 + r;
                int col = colBase + wn * 64 + n * 16 + l15;
                f16 hv = (f16)acc[m][n][r];
                int b = row >> 10, nt = row & 1023;
                int which = col >> 9, hh = (col >> 6) & 7, d = col & 63;
                size_t hidx = ((size_t)(b * 8 + hh) * 1024 + nt) * 64 + d;
                if (which == 0)      q[hidx] = hv;
                else if (which == 1) kmat[hidx] = hv;
                else                 vt[((size_t)(b * 8 + hh) * 64 + d) * 1024 + nt] = hv;
            }
}

// ---- masked flash attention v5: LDS dbuf 64-token chunks, swizzled, 2-phase ----
// 1024 blocks x 256 threads; wave = 16 q-rows; one barrier per chunk.
__global__ __launch_bounds__(256, 4) void k_attn(
    const f16* __restrict__ q, const f16* __restrict__ kmat,
    const f16* __restrict__ vt, const int* __restrict__ mlab,
    f16* __restrict__ ao)
{
    __shared__ f16 Ks[2][64 * 64];
    __shared__ f16 Vs[2][64 * 64];

    int bid = blockIdx.x;
    int bh = (bid & 7) + 8 * (bid >> 7);      // all 16 q-blocks of a bh on one XCD
    int qb = (bid >> 3) & 15;
    int b = bh >> 3, hh = bh & 7;
    int tid = threadIdx.x, wid = tid >> 6, lane = tid & 63;
    int l15 = lane & 15, l4 = lane >> 4;
    int qbase = qb * 64;
    size_t bhs = (size_t)bh;

    if (mlab[b * 4 + (qb >> 2)] == 0) return;  // out rows filled by k_gemm_out bias path

    // present 64-token chunks, 4 bits each (value = t0/64), up to 16
    unsigned long long chpack = 0; int nch = 0;
#pragma unroll
    for (int s = 0; s < 4; ++s)
        if (mlab[b * 4 + s] != 0) {
#pragma unroll
            for (int j = 0; j < 4; ++j) {
                chpack |= (unsigned long long)(4 * s + j) << (4 * nch);
                ++nch;
            }
        }

    // Q fragment for this wave's 16 q rows, pre-scaled by 1/8
    f16x8 qf[2];
#pragma unroll
    for (int kk = 0; kk < 2; ++kk) {
        qf[kk] = *(const f16x8*)&q[(bhs * 1024 + qbase + wid * 16 + l15) * 64 + kk * 32 + l4 * 8];
#pragma unroll
        for (int j = 0; j < 8; ++j) qf[kk][j] = qf[kk][j] * (f16)0.125;
    }

    // staging geometry: 512 16B-slots per tile; thread covers slots tid, tid+256.
    // inverse-swizzled source column so swizzled READS are conflict-free (rule #21)
    int srow0 = tid >> 3;
    int sc0 = (((tid & 7) ^ (srow0 & 7)) << 3);
    int srow1 = (tid + 256) >> 3;
    int sc1 = ((((tid + 256) & 7) ^ (srow1 & 7)) << 3);
    int ldsbase0 = (wid * 64) * 8;            // f16 offset, wave-uniform
    int ldsbase1 = (wid * 64 + 256) * 8;

#define STAGE(bi, t0)                                                                   \
    do {                                                                                \
        GLD16(&kmat[(bhs * 1024 + (t0) + srow0) * 64 + sc0], &Ks[bi][ldsbase0]);        \
        GLD16(&kmat[(bhs * 1024 + (t0) + srow1) * 64 + sc1], &Ks[bi][ldsbase1]);        \
        GLD16(&vt[(bhs * 64 + srow0) * 1024 + (t0) + sc0],   &Vs[bi][ldsbase0]);        \
        GLD16(&vt[(bhs * 64 + srow1) * 1024 + (t0) + sc1],   &Vs[bi][ldsbase1]);        \
    } while (0)

    float mrun = -1e30f, lrun = 0.f;
    f32x4 o[4] = {};
    int kxor = (l15 & 7) << 3;
    int srcA = l15 + ((l4 & 1) * 2) * 16;
    int srcB = srcA + 16;
    int sel = l4 >> 1;

    STAGE(0, (int)(chpack & 15) << 6);

    for (int c = 0; c < nch; ++c) {
        int bi = c & 1;
        if (c + 1 < nch) {
            int t0n = (int)((chpack >> (4 * (c + 1))) & 15) << 6;
            STAGE(bi ^ 1, t0n);
        }
        __syncthreads();                       // buf bi staged (drains vmcnt)

        // QK^T swapped: st[n] = S^T, k = n*16 + l4*4 + r, q-col = l15
        f32x4 st[4] = {};
#pragma unroll
        for (int kk = 0; kk < 2; ++kk)
#pragma unroll
            for (int n = 0; n < 4; ++n) {
                f16x8 ka = *(const f16x8*)&Ks[bi][(n * 16 + l15) * 64 + ((kk * 32 + l4 * 8) ^ kxor)];
                st[n] = mfma16(ka, qf[kk], st[n]);
            }

        // lane-local online softmax over this lane's 16 k-values
        f32x4 m4 = st[0];
#pragma unroll
        for (int n = 1; n < 4; ++n)
#pragma unroll
            for (int r = 0; r < 4; ++r) m4[r] = fmaxf(m4[r], st[n][r]);
        float mx = fmaxf(fmaxf(m4[0], m4[1]), fmaxf(m4[2], m4[3]));
        mx = fmaxf(mx, __shfl_xor(mx, 16));
        mx = fmaxf(mx, __shfl_xor(mx, 32));
        float mnew = fmaxf(mrun, mx);
        float alpha = __expf(mrun - mnew);
        mrun = mnew;
        float rs = 0.f;
        union PK { f16 h[4]; long long ll; } pk[4];
#pragma unroll
        for (int n = 0; n < 4; ++n)
#pragma unroll
            for (int r = 0; r < 4; ++r) {
                float p = __expf(st[n][r] - mnew);
                rs += p;
                pk[n].h[r] = (f16)p;
            }
        rs += __shfl_xor(rs, 16);
        rs += __shfl_xor(rs, 32);
        lrun = lrun * alpha + rs;
#pragma unroll
        for (int nd = 0; nd < 4; ++nd) o[nd] *= alpha;

        // P redistribution within 4-lane groups + PV (2 ks steps of 32 k)
#pragma unroll
        for (int ks = 0; ks < 2; ++ks) {
            long long A0 = __shfl(pk[ks * 2].ll,     srcA);
            long long A1 = __shfl(pk[ks * 2 + 1].ll, srcA);
            long long B0 = __shfl(pk[ks * 2].ll,     srcB);
            long long B1 = __shfl(pk[ks * 2 + 1].ll, srcB);
            union PB { long long ll[2]; f16x8 v; } pb;
            pb.ll[0] = sel ? A1 : A0;
            pb.ll[1] = sel ? B1 : B0;
#pragma unroll
            for (int nd = 0; nd < 4; ++nd) {
                f16x8 va = *(const f16x8*)&Vs[bi][(nd * 16 + l15) * 64 + ((ks * 32 + l4 * 8) ^ kxor)];
                o[nd] = mfma16(va, pb.v, o[nd]);
            }
        }
        __syncthreads();                       // all waves done with buf bi
    }
#undef STAGE

    float inv = 1.f / lrun;
    int qrow = qbase + wid * 16 + l15;
#pragma unroll
    for (int nd = 0; nd < 4; ++nd) {
        union { f16 h[4]; long long ll; } w;
#pragma unroll
        for (int r = 0; r < 4; ++r) w.h[r] = (f16)(o[nd][r] * inv);
        *(long long*)&ao[(size_t)(b * 1024 + qrow) * 512 + hh * 64 + nd * 16 + l4 * 4] = w.ll;
    }
}

// ---- out GEMM (64x128 tile, BK=64, global_load_lds, bias-fill for zero rows) ----
__global__ __launch_bounds__(256) void k_gemm_out(
    const f16* __restrict__ A, const f16* __restrict__ Bt, const int* __restrict__ mlab,
    const float* __restrict__ bias, float* __restrict__ out)
{
    __shared__ f16 As[64 * 64];
    __shared__ f16 Bs[128 * 64];
    int tid = threadIdx.x, wid = tid >> 6, lane = tid & 63;
    int wm = wid >> 1, wn = wid & 1;
    int l15 = lane & 15, l4 = lane >> 4;
    int rowBase = blockIdx.y * 64;
    int colBase = blockIdx.x * 128;
    int bb = rowBase >> 10, seg = (rowBase & 1023) >> 8;
    if (mlab[bb * 4 + seg] == 0) {
        for (int i = tid; i < 64 * 128; i += 256)
            out[(size_t)(rowBase + (i >> 7)) * 512 + colBase + (i & 127)] = bias[colBase + (i & 127)];
        return;
    }

    int srow = lane >> 3, scol = (lane & 7) * 8;
    f32x4 acc[2][4] = {};
    for (int kt = 0; kt < 512; kt += 64) {
#pragma unroll
        for (int i = 0; i < 2; ++i) {
            int rg = (wid * 2 + i) * 8;
            GLD16(&A[(size_t)(rowBase + rg + srow) * 512 + kt + scol], &As[rg * 64]);
        }
#pragma unroll
        for (int i = 0; i < 4; ++i) {
            int rg = (wid * 4 + i) * 8;
            GLD16(&Bt[(size_t)(colBase + rg + srow) * 512 + kt + scol], &Bs[rg * 64]);
        }
        __syncthreads();
#pragma unroll
        for (int kk = 0; kk < 2; ++kk) {
            f16x8 af[2], bf[4];
#pragma unroll
            for (int m = 0; m < 2; ++m) af[m] = *(const f16x8*)&As[(wm * 32 + m * 16 + l15) * 64 + kk * 32 + l4 * 8];
#pragma unroll
            for (int n = 0; n < 4; ++n) bf[n] = *(const f16x8*)&Bs[(wn * 64 + n * 16 + l15) * 64 + kk * 32 + l4 * 8];
#pragma unroll
            for (int m = 0; m < 2; ++m)
#pragma unroll
                for (int n = 0; n < 4; ++n)
                    acc[m][n] = mfma16(af[m], bf[n], acc[m][n]);
        }
        __syncthreads();
    }
#pragma unroll
    for (int m = 0; m < 2; ++m)
#pragma unroll
        for (int n = 0; n < 4; ++n)
#pragma unroll
            for (int r = 0; r < 4; ++r) {
                int row = rowBase + wm * 32 + m * 16 + l4 * 4 + r;
                int col = colBase + wn * 64 + n * 16 + l15;
                out[(size_t)row * 512 + col] = acc[m][n][r] + bias[col];
            }
}

extern "C" void kernel_launch(void* const* d_in, const int* in_sizes, int n_in,
                              void* d_out, int out_size, void* d_ws, size_t ws_size,
                              hipStream_t stream) {
    const float* x     = (const float*)d_in[0];
    const int*   mlab  = (const int*)d_in[1];
    const float* gamma = (const float*)d_in[2];
    const float* beta  = (const float*)d_in[3];
    const float* wqkv  = (const float*)d_in[4];
    const float* wout  = (const float*)d_in[5];
    const float* bout  = (const float*)d_in[6];
    float* out = (float*)d_out;

    f16* h     = (f16*)d_ws;                 // 8192*512
    f16* wqkvT = h + 8192 * 512;             // 1536*512
    f16* woutT = wqkvT + 1536 * 512;         // 512*512
    f16* q     = woutT + 512 * 512;          // [B*H][1024][64]
    f16* kmat  = q + 4 * 1024 * 1024;
    f16* vt    = kmat + 4 * 1024 * 1024;     // [B*H][64][1024]
    f16* ao    = h;                          // h dead after QKV GEMM -> reuse

    k_wtrans<<<dim3(24, 8), 256, 0, stream>>>(wqkv, wqkvT, 1536);
    k_wtrans<<<dim3(8, 8), 256, 0, stream>>>(wout, woutT, 512);
    k_ln<<<2048, 256, 0, stream>>>(x, gamma, beta, mlab, h);
    k_gemm_qkv<<<dim3(12, 64), 256, 0, stream>>>(h, wqkvT, mlab, q, kmat, vt);
    k_attn<<<1024, 256, 0, stream>>>(q, kmat, vt, mlab, ao);
    k_gemm_out<<<dim3(4, 128), 256, 0, stream>>>(ao, woutT, mlab, bout, out);
}

// Round 6
// 73.671 us; speedup vs baseline: 1.6508x; 1.1598x over previous
//
#include <hip/hip_runtime.h>

typedef _Float16 f16;
typedef _Float16 f16x8 __attribute__((ext_vector_type(8)));
typedef float f32x4 __attribute__((ext_vector_type(4)));

typedef __attribute__((address_space(1))) void gvoid;
typedef __attribute__((address_space(3))) void lvoid;
#define GLD16(gp, lp) __builtin_amdgcn_global_load_lds((gvoid*)(gp), (lvoid*)(lp), 16, 0, 0)

__device__ __forceinline__ f32x4 mfma16(f16x8 a, f16x8 b, f32x4 c) {
    return __builtin_amdgcn_mfma_f32_16x16x32_f16(a, b, c, 0, 0, 0);
}

// ---- prep: LN (blocks 0..2047) + wqkv transpose (2048..2239) + wout transpose (2240..2303)
__global__ __launch_bounds__(256) void k_prep(
    const float* __restrict__ x, const float* __restrict__ gamma,
    const float* __restrict__ beta, const int* __restrict__ mlab,
    const float* __restrict__ wqkv, const float* __restrict__ wout,
    f16* __restrict__ h, f16* __restrict__ wqkvT, f16* __restrict__ woutT)
{
    __shared__ float t[64][65];
    int bid = blockIdx.x, tid = threadIdx.x;
    if (bid < 2048) {                       // ---- LayerNorm, 1 wave/row ----
        int row = bid * 4 + (tid >> 6);
        int b = row >> 10, seg = (row >> 8) & 3;
        if (mlab[b * 4 + seg] == 0) return; // h rows of missing segs never read
        int lane = tid & 63;
        const float* xr = x + (size_t)row * 512;
        float4 a = ((const float4*)xr)[lane * 2];
        float4 bv = ((const float4*)xr)[lane * 2 + 1];
        float v[8] = {a.x, a.y, a.z, a.w, bv.x, bv.y, bv.z, bv.w};
        float s = 0.f, s2 = 0.f;
#pragma unroll
        for (int j = 0; j < 8; ++j) { s += v[j]; s2 += v[j] * v[j]; }
#pragma unroll
        for (int off = 1; off < 64; off <<= 1) {
            s  += __shfl_xor(s, off);
            s2 += __shfl_xor(s2, off);
        }
        float mu  = s * (1.f / 512.f);
        float var = s2 * (1.f / 512.f) - mu * mu;
        float rstd = rsqrtf(var + 1e-5f);
        float4 g0 = ((const float4*)gamma)[lane * 2];
        float4 g1 = ((const float4*)gamma)[lane * 2 + 1];
        float4 b0 = ((const float4*)beta)[lane * 2];
        float4 b1 = ((const float4*)beta)[lane * 2 + 1];
        float g[8]  = {g0.x, g0.y, g0.z, g0.w, g1.x, g1.y, g1.z, g1.w};
        float bb[8] = {b0.x, b0.y, b0.z, b0.w, b1.x, b1.y, b1.z, b1.w};
        f16x8 o;
#pragma unroll
        for (int j = 0; j < 8; ++j) o[j] = (f16)((v[j] - mu) * rstd * g[j] + bb[j]);
        *(f16x8*)&h[(size_t)row * 512 + lane * 8] = o;
        return;
    }
    // ---- weight transpose + f16 cast via LDS tile ----
    const float* in; f16* out; int C, c0, r0;
    if (bid < 2240) { int idx = bid - 2048; in = wqkv; out = wqkvT; C = 1536; c0 = (idx % 24) * 64; r0 = (idx / 24) * 64; }
    else            { int idx = bid - 2240; in = wout; out = woutT; C = 512;  c0 = (idx % 8)  * 64; r0 = (idx / 8)  * 64; }
#pragma unroll
    for (int i = 0; i < 16; ++i) {
        int r = i * 4 + (tid >> 6), c = tid & 63;
        t[r][c] = in[(size_t)(r0 + r) * C + c0 + c];
    }
    __syncthreads();
#pragma unroll
    for (int i = 0; i < 16; ++i) {
        int cr = i * 4 + (tid >> 6), cc = tid & 63;
        out[(size_t)(c0 + cr) * 512 + r0 + cc] = (f16)t[cc][cr];
    }
}

// ---- QKV GEMM: 64x128 tile, BK=64, LDS dbuf, single barrier/K-step, swizzled ----
__global__ __launch_bounds__(256, 3) void k_gemm_qkv(
    const f16* __restrict__ A, const f16* __restrict__ Bt, const int* __restrict__ mlab,
    f16* __restrict__ q, f16* __restrict__ kmat, f16* __restrict__ vt)
{
    __shared__ f16 As[2][64 * 64];
    __shared__ f16 Bs[2][128 * 64];
    int tid = threadIdx.x, wid = tid >> 6, lane = tid & 63;
    int wm = wid >> 1, wn = wid & 1;
    int l15 = lane & 15, l4 = lane >> 4;
    int rowBase = blockIdx.y * 64;
    int colBase = blockIdx.x * 128;
    if (mlab[(rowBase >> 10) * 4 + ((rowBase & 1023) >> 8)] == 0) return;

    int srow = lane >> 3;
    int scolz = ((lane & 7) ^ srow) << 3;    // inverse-swizzled source col (rule #21)
    int kxor = (l15 & 7) << 3;

#define STG(bi, kt)                                                                         \
    do {                                                                                    \
        _Pragma("unroll") for (int i_ = 0; i_ < 2; ++i_) {                                  \
            int rg = (wid * 2 + i_) * 8;                                                    \
            GLD16(&A[(size_t)(rowBase + rg + srow) * 512 + (kt) + scolz], &As[bi][rg * 64]);\
        }                                                                                   \
        _Pragma("unroll") for (int i_ = 0; i_ < 4; ++i_) {                                  \
            int rg = (wid * 4 + i_) * 8;                                                    \
            GLD16(&Bt[(size_t)(colBase + rg + srow) * 512 + (kt) + scolz], &Bs[bi][rg * 64]);\
        }                                                                                   \
    } while (0)

    f32x4 acc[2][4] = {};
    STG(0, 0);
    for (int ki = 0; ki < 8; ++ki) {
        int bi = ki & 1;
        __syncthreads();                    // buf bi staged; all waves done with bi^1
        if (ki < 7) STG(bi ^ 1, (ki + 1) * 64);
#pragma unroll
        for (int kk = 0; kk < 2; ++kk) {
            f16x8 af[2], bf[4];
#pragma unroll
            for (int m = 0; m < 2; ++m)
                af[m] = *(const f16x8*)&As[bi][(wm * 32 + m * 16 + l15) * 64 + ((kk * 32 + l4 * 8) ^ kxor)];
#pragma unroll
            for (int n = 0; n < 4; ++n)
                bf[n] = *(const f16x8*)&Bs[bi][(wn * 64 + n * 16 + l15) * 64 + ((kk * 32 + l4 * 8) ^ kxor)];
#pragma unroll
            for (int m = 0; m < 2; ++m)
#pragma unroll
                for (int n = 0; n < 4; ++n)
                    acc[m][n] = mfma16(af[m], bf[n], acc[m][n]);
        }
    }
#undef STG
#pragma unroll
    for (int m = 0; m < 2; ++m)
#pragma unroll
        for (int n = 0; n < 4; ++n)
#pragma unroll
            for (int r = 0; r < 4; ++r) {
                int row = rowBase + wm * 32 + m * 16 + l4 * 4 + r;
                int col = colBase + wn * 64 + n * 16 + l15;
                f16 hv = (f16)acc[m][n][r];
                int b = row >> 10, nt = row & 1023;
                int which = col >> 9, hh = (col >> 6) & 7, d = col & 63;
                size_t hidx = ((size_t)(b * 8 + hh) * 1024 + nt) * 64 + d;
                if (which == 0)      q[hidx] = hv;
                else if (which == 1) kmat[hidx] = hv;
                else                 vt[((size_t)(b * 8 + hh) * 64 + d) * 1024 + nt] = hv;
            }
}

// ---- masked flash attention v6: LDS dbuf, ONE barrier/chunk, stage-after-barrier ----
__global__ __launch_bounds__(256, 5) void k_attn(
    const f16* __restrict__ q, const f16* __restrict__ kmat,
    const f16* __restrict__ vt, const int* __restrict__ mlab,
    f16* __restrict__ ao)
{
    __shared__ f16 Ks[2][64 * 64];
    __shared__ f16 Vs[2][64 * 64];

    int bid = blockIdx.x;
    int bh = (bid & 7) + 8 * (bid >> 7);      // all 16 q-blocks of a bh on one XCD
    int qb = (bid >> 3) & 15;
    int b = bh >> 3, hh = bh & 7;
    int tid = threadIdx.x, wid = tid >> 6, lane = tid & 63;
    int l15 = lane & 15, l4 = lane >> 4;
    int qbase = qb * 64;
    size_t bhs = (size_t)bh;

    if (mlab[b * 4 + (qb >> 2)] == 0) return;  // rows filled by k_gemm_out bias path

    unsigned long long chpack = 0; int nch = 0;
#pragma unroll
    for (int s = 0; s < 4; ++s)
        if (mlab[b * 4 + s] != 0) {
#pragma unroll
            for (int j = 0; j < 4; ++j) {
                chpack |= (unsigned long long)(4 * s + j) << (4 * nch);
                ++nch;
            }
        }

    f16x8 qf[2];
#pragma unroll
    for (int kk = 0; kk < 2; ++kk) {
        qf[kk] = *(const f16x8*)&q[(bhs * 1024 + qbase + wid * 16 + l15) * 64 + kk * 32 + l4 * 8];
#pragma unroll
        for (int j = 0; j < 8; ++j) qf[kk][j] = qf[kk][j] * (f16)0.125;
    }

    int srow0 = tid >> 3;
    int sc0 = ((tid & 7) ^ (srow0 & 7)) << 3;
    int srow1 = (tid + 256) >> 3;
    int sc1 = (((tid + 256) & 7) ^ (srow1 & 7)) << 3;
    int ldsbase0 = (wid * 64) * 8;
    int ldsbase1 = (wid * 64 + 256) * 8;

#define STAGE(bi, t0)                                                                   \
    do {                                                                                \
        GLD16(&kmat[(bhs * 1024 + (t0) + srow0) * 64 + sc0], &Ks[bi][ldsbase0]);        \
        GLD16(&kmat[(bhs * 1024 + (t0) + srow1) * 64 + sc1], &Ks[bi][ldsbase1]);        \
        GLD16(&vt[(bhs * 64 + srow0) * 1024 + (t0) + sc0],   &Vs[bi][ldsbase0]);        \
        GLD16(&vt[(bhs * 64 + srow1) * 1024 + (t0) + sc1],   &Vs[bi][ldsbase1]);        \
    } while (0)

    float mrun = -1e30f, lrun = 0.f;
    f32x4 o[4] = {};
    int kxor = (l15 & 7) << 3;
    int srcA = l15 + ((l4 & 1) * 2) * 16;
    int srcB = srcA + 16;
    int sel = l4 >> 1;

    STAGE(0, (int)(chpack & 15) << 6);

    for (int c = 0; c < nch; ++c) {
        int bi = c & 1;
        __syncthreads();                       // buf bi ready; bi^1 free to overwrite
        if (c + 1 < nch) {                     // prefetch hides under this chunk's compute
            int t0n = (int)((chpack >> (4 * (c + 1))) & 15) << 6;
            STAGE(bi ^ 1, t0n);
        }

        // QK^T swapped: st[n] = S^T, k = n*16 + l4*4 + r, q-col = l15
        f32x4 st[4] = {};
#pragma unroll
        for (int kk = 0; kk < 2; ++kk)
#pragma unroll
            for (int n = 0; n < 4; ++n) {
                f16x8 ka = *(const f16x8*)&Ks[bi][(n * 16 + l15) * 64 + ((kk * 32 + l4 * 8) ^ kxor)];
                st[n] = mfma16(ka, qf[kk], st[n]);
            }

        // lane-local online softmax over this lane's 16 k-values
        f32x4 m4 = st[0];
#pragma unroll
        for (int n = 1; n < 4; ++n)
#pragma unroll
            for (int r = 0; r < 4; ++r) m4[r] = fmaxf(m4[r], st[n][r]);
        float mx = fmaxf(fmaxf(m4[0], m4[1]), fmaxf(m4[2], m4[3]));
        mx = fmaxf(mx, __shfl_xor(mx, 16));
        mx = fmaxf(mx, __shfl_xor(mx, 32));
        float mnew = fmaxf(mrun, mx);
        float alpha = __expf(mrun - mnew);
        mrun = mnew;
        float rs = 0.f;
        union PK { f16 h[4]; long long ll; } pk[4];
#pragma unroll
        for (int n = 0; n < 4; ++n)
#pragma unroll
            for (int r = 0; r < 4; ++r) {
                float p = __expf(st[n][r] - mnew);
                rs += p;
                pk[n].h[r] = (f16)p;
            }
        rs += __shfl_xor(rs, 16);
        rs += __shfl_xor(rs, 32);
        lrun = lrun * alpha + rs;
#pragma unroll
        for (int nd = 0; nd < 4; ++nd) o[nd] *= alpha;

        // P redistribution within 4-lane groups + PV
#pragma unroll
        for (int ks = 0; ks < 2; ++ks) {
            long long A0 = __shfl(pk[ks * 2].ll,     srcA);
            long long A1 = __shfl(pk[ks * 2 + 1].ll, srcA);
            long long B0 = __shfl(pk[ks * 2].ll,     srcB);
            long long B1 = __shfl(pk[ks * 2 + 1].ll, srcB);
            union PB { long long ll[2]; f16x8 v; } pb;
            pb.ll[0] = sel ? A1 : A0;
            pb.ll[1] = sel ? B1 : B0;
#pragma unroll
            for (int nd = 0; nd < 4; ++nd) {
                f16x8 va = *(const f16x8*)&Vs[bi][(nd * 16 + l15) * 64 + ((ks * 32 + l4 * 8) ^ kxor)];
                o[nd] = mfma16(va, pb.v, o[nd]);
            }
        }
    }
#undef STAGE

    float inv = 1.f / lrun;
    int qrow = qbase + wid * 16 + l15;
#pragma unroll
    for (int nd = 0; nd < 4; ++nd) {
        union { f16 h[4]; long long ll; } w;
#pragma unroll
        for (int r = 0; r < 4; ++r) w.h[r] = (f16)(o[nd][r] * inv);
        *(long long*)&ao[(size_t)(b * 1024 + qrow) * 512 + hh * 64 + nd * 16 + l4 * 4] = w.ll;
    }
}

// ---- out GEMM: 64x128 tile, LDS dbuf, single barrier/K-step, swizzled ----
__global__ __launch_bounds__(256, 3) void k_gemm_out(
    const f16* __restrict__ A, const f16* __restrict__ Bt, const int* __restrict__ mlab,
    const float* __restrict__ bias, float* __restrict__ out)
{
    __shared__ f16 As[2][64 * 64];
    __shared__ f16 Bs[2][128 * 64];
    int tid = threadIdx.x, wid = tid >> 6, lane = tid & 63;
    int wm = wid >> 1, wn = wid & 1;
    int l15 = lane & 15, l4 = lane >> 4;
    int rowBase = blockIdx.y * 64;
    int colBase = blockIdx.x * 128;
    if (mlab[(rowBase >> 10) * 4 + ((rowBase & 1023) >> 8)] == 0) {
        for (int i = tid; i < 64 * 128; i += 256)
            out[(size_t)(rowBase + (i >> 7)) * 512 + colBase + (i & 127)] = bias[colBase + (i & 127)];
        return;
    }

    int srow = lane >> 3;
    int scolz = ((lane & 7) ^ srow) << 3;
    int kxor = (l15 & 7) << 3;

#define STG(bi, kt)                                                                         \
    do {                                                                                    \
        _Pragma("unroll") for (int i_ = 0; i_ < 2; ++i_) {                                  \
            int rg = (wid * 2 + i_) * 8;                                                    \
            GLD16(&A[(size_t)(rowBase + rg + srow) * 512 + (kt) + scolz], &As[bi][rg * 64]);\
        }                                                                                   \
        _Pragma("unroll") for (int i_ = 0; i_ < 4; ++i_) {                                  \
            int rg = (wid * 4 + i_) * 8;                                                    \
            GLD16(&Bt[(size_t)(colBase + rg + srow) * 512 + (kt) + scolz], &Bs[bi][rg * 64]);\
        }                                                                                   \
    } while (0)

    f32x4 acc[2][4] = {};
    STG(0, 0);
    for (int ki = 0; ki < 8; ++ki) {
        int bi = ki & 1;
        __syncthreads();
        if (ki < 7) STG(bi ^ 1, (ki + 1) * 64);
#pragma unroll
        for (int kk = 0; kk < 2; ++kk) {
            f16x8 af[2], bf[4];
#pragma unroll
            for (int m = 0; m < 2; ++m)
                af[m] = *(const f16x8*)&As[bi][(wm * 32 + m * 16 + l15) * 64 + ((kk * 32 + l4 * 8) ^ kxor)];
#pragma unroll
            for (int n = 0; n < 4; ++n)
                bf[n] = *(const f16x8*)&Bs[bi][(wn * 64 + n * 16 + l15) * 64 + ((kk * 32 + l4 * 8) ^ kxor)];
#pragma unroll
            for (int m = 0; m < 2; ++m)
#pragma unroll
                for (int n = 0; n < 4; ++n)
                    acc[m][n] = mfma16(af[m], bf[n], acc[m][n]);
        }
    }
#undef STG
#pragma unroll
    for (int m = 0; m < 2; ++m)
#pragma unroll
        for (int n = 0; n < 4; ++n)
#pragma unroll
            for (int r = 0; r < 4; ++r) {
                int row = rowBase + wm * 32 + m * 16 + l4 * 4 + r;
                int col = colBase + wn * 64 + n * 16 + l15;
                out[(size_t)row * 512 + col] = acc[m][n][r] + bias[col];
            }
}

extern "C" void kernel_launch(void* const* d_in, const int* in_sizes, int n_in,
                              void* d_out, int out_size, void* d_ws, size_t ws_size,
                              hipStream_t stream) {
    const float* x     = (const float*)d_in[0];
    const int*   mlab  = (const int*)d_in[1];
    const float* gamma = (const float*)d_in[2];
    const float* beta  = (const float*)d_in[3];
    const float* wqkv  = (const float*)d_in[4];
    const float* wout  = (const float*)d_in[5];
    const float* bout  = (const float*)d_in[6];
    float* out = (float*)d_out;

    f16* h     = (f16*)d_ws;                 // 8192*512
    f16* wqkvT = h + 8192 * 512;             // 1536*512
    f16* woutT = wqkvT + 1536 * 512;         // 512*512
    f16* q     = woutT + 512 * 512;          // [B*H][1024][64]
    f16* kmat  = q + 4 * 1024 * 1024;
    f16* vt    = kmat + 4 * 1024 * 1024;     // [B*H][64][1024]
    f16* ao    = h;                          // h dead after QKV GEMM -> reuse

    k_prep<<<2304, 256, 0, stream>>>(x, gamma, beta, mlab, wqkv, wout, h, wqkvT, woutT);
    k_gemm_qkv<<<dim3(12, 128), 256, 0, stream>>>(h, wqkvT, mlab, q, kmat, vt);
    k_attn<<<1024, 256, 0, stream>>>(q, kmat, vt, mlab, ao);
    k_gemm_out<<<dim3(4, 128), 256, 0, stream>>>(ao, woutT, mlab, bout, out);
}

// Round 7
// 68.934 us; speedup vs baseline: 1.7642x; 1.0687x over previous
//
#include <hip/hip_runtime.h>

typedef _Float16 f16;
typedef _Float16 f16x8 __attribute__((ext_vector_type(8)));
typedef float f32x4 __attribute__((ext_vector_type(4)));

typedef __attribute__((address_space(1))) void gvoid;
typedef __attribute__((address_space(3))) void lvoid;
#define GLD16(gp, lp) __builtin_amdgcn_global_load_lds((gvoid*)(gp), (lvoid*)(lp), 16, 0, 0)

__device__ __forceinline__ f32x4 mfma16(f16x8 a, f16x8 b, f32x4 c) {
    return __builtin_amdgcn_mfma_f32_16x16x32_f16(a, b, c, 0, 0, 0);
}

// ---- prep: LN (blocks 0..2047) + wqkv transpose (2048..2239) + wout transpose (2240..2303)
__global__ __launch_bounds__(256) void k_prep(
    const float* __restrict__ x, const float* __restrict__ gamma,
    const float* __restrict__ beta, const int* __restrict__ mlab,
    const float* __restrict__ wqkv, const float* __restrict__ wout,
    f16* __restrict__ h, f16* __restrict__ wqkvT, f16* __restrict__ woutT)
{
    __shared__ float t[64][65];
    int bid = blockIdx.x, tid = threadIdx.x;
    if (bid < 2048) {                       // ---- LayerNorm, 1 wave/row ----
        int row = bid * 4 + (tid >> 6);
        int b = row >> 10, seg = (row >> 8) & 3;
        if (mlab[b * 4 + seg] == 0) return; // h rows of missing segs never read
        int lane = tid & 63;
        const float* xr = x + (size_t)row * 512;
        float4 a = ((const float4*)xr)[lane * 2];
        float4 bv = ((const float4*)xr)[lane * 2 + 1];
        float v[8] = {a.x, a.y, a.z, a.w, bv.x, bv.y, bv.z, bv.w};
        float s = 0.f, s2 = 0.f;
#pragma unroll
        for (int j = 0; j < 8; ++j) { s += v[j]; s2 += v[j] * v[j]; }
#pragma unroll
        for (int off = 1; off < 64; off <<= 1) {
            s  += __shfl_xor(s, off);
            s2 += __shfl_xor(s2, off);
        }
        float mu  = s * (1.f / 512.f);
        float var = s2 * (1.f / 512.f) - mu * mu;
        float rstd = rsqrtf(var + 1e-5f);
        float4 g0 = ((const float4*)gamma)[lane * 2];
        float4 g1 = ((const float4*)gamma)[lane * 2 + 1];
        float4 b0 = ((const float4*)beta)[lane * 2];
        float4 b1 = ((const float4*)beta)[lane * 2 + 1];
        float g[8]  = {g0.x, g0.y, g0.z, g0.w, g1.x, g1.y, g1.z, g1.w};
        float bb[8] = {b0.x, b0.y, b0.z, b0.w, b1.x, b1.y, b1.z, b1.w};
        f16x8 o;
#pragma unroll
        for (int j = 0; j < 8; ++j) o[j] = (f16)((v[j] - mu) * rstd * g[j] + bb[j]);
        *(f16x8*)&h[(size_t)row * 512 + lane * 8] = o;
        return;
    }
    // ---- weight transpose + f16 cast via LDS tile ----
    const float* in; f16* out; int C, c0, r0;
    if (bid < 2240) { int idx = bid - 2048; in = wqkv; out = wqkvT; C = 1536; c0 = (idx % 24) * 64; r0 = (idx / 24) * 64; }
    else            { int idx = bid - 2240; in = wout; out = woutT; C = 512;  c0 = (idx % 8)  * 64; r0 = (idx / 8)  * 64; }
#pragma unroll
    for (int i = 0; i < 16; ++i) {
        int r = i * 4 + (tid >> 6), c = tid & 63;
        t[r][c] = in[(size_t)(r0 + r) * C + c0 + c];
    }
    __syncthreads();
#pragma unroll
    for (int i = 0; i < 16; ++i) {
        int cr = i * 4 + (tid >> 6), cc = tid & 63;
        out[(size_t)(c0 + cr) * 512 + r0 + cc] = (f16)t[cc][cr];
    }
}

// ---- QKV GEMM: 64x128 tile, BK=64, LDS dbuf, single barrier/K-step, swizzled ----
__global__ __launch_bounds__(256, 3) void k_gemm_qkv(
    const f16* __restrict__ A, const f16* __restrict__ Bt, const int* __restrict__ mlab,
    f16* __restrict__ q, f16* __restrict__ kmat, f16* __restrict__ vt)
{
    __shared__ f16 As[2][64 * 64];
    __shared__ f16 Bs[2][128 * 64];
    int tid = threadIdx.x, wid = tid >> 6, lane = tid & 63;
    int wm = wid >> 1, wn = wid & 1;
    int l15 = lane & 15, l4 = lane >> 4;
    int rowBase = blockIdx.y * 64;
    int colBase = blockIdx.x * 128;
    if (mlab[(rowBase >> 10) * 4 + ((rowBase & 1023) >> 8)] == 0) return;

    int srow = lane >> 3;
    int scolz = ((lane & 7) ^ srow) << 3;    // inverse-swizzled source col (rule #21)
    int kxor = (l15 & 7) << 3;

#define STG(bi, kt)                                                                         \
    do {                                                                                    \
        _Pragma("unroll") for (int i_ = 0; i_ < 2; ++i_) {                                  \
            int rg = (wid * 2 + i_) * 8;                                                    \
            GLD16(&A[(size_t)(rowBase + rg + srow) * 512 + (kt) + scolz], &As[bi][rg * 64]);\
        }                                                                                   \
        _Pragma("unroll") for (int i_ = 0; i_ < 4; ++i_) {                                  \
            int rg = (wid * 4 + i_) * 8;                                                    \
            GLD16(&Bt[(size_t)(colBase + rg + srow) * 512 + (kt) + scolz], &Bs[bi][rg * 64]);\
        }                                                                                   \
    } while (0)

    f32x4 acc[2][4] = {};
    STG(0, 0);
    for (int ki = 0; ki < 8; ++ki) {
        int bi = ki & 1;
        __syncthreads();                    // buf bi staged; all waves done with bi^1
        if (ki < 7) STG(bi ^ 1, (ki + 1) * 64);
#pragma unroll
        for (int kk = 0; kk < 2; ++kk) {
            f16x8 af[2], bf[4];
#pragma unroll
            for (int m = 0; m < 2; ++m)
                af[m] = *(const f16x8*)&As[bi][(wm * 32 + m * 16 + l15) * 64 + ((kk * 32 + l4 * 8) ^ kxor)];
#pragma unroll
            for (int n = 0; n < 4; ++n)
                bf[n] = *(const f16x8*)&Bs[bi][(wn * 64 + n * 16 + l15) * 64 + ((kk * 32 + l4 * 8) ^ kxor)];
#pragma unroll
            for (int m = 0; m < 2; ++m)
#pragma unroll
                for (int n = 0; n < 4; ++n)
                    acc[m][n] = mfma16(af[m], bf[n], acc[m][n]);
        }
    }
#undef STG
#pragma unroll
    for (int m = 0; m < 2; ++m)
#pragma unroll
        for (int n = 0; n < 4; ++n)
#pragma unroll
            for (int r = 0; r < 4; ++r) {
                int row = rowBase + wm * 32 + m * 16 + l4 * 4 + r;
                int col = colBase + wn * 64 + n * 16 + l15;
                f16 hv = (f16)acc[m][n][r];
                int b = row >> 10, nt = row & 1023;
                int which = col >> 9, hh = (col >> 6) & 7, d = col & 63;
                size_t hidx = ((size_t)(b * 8 + hh) * 1024 + nt) * 64 + d;
                if (which == 0)      q[hidx] = hv;
                else if (which == 1) kmat[hidx] = hv;
                else                 vt[((size_t)(b * 8 + hh) * 64 + d) * 1024 + nt] = hv;
            }
}

// ---- masked flash attention v7: split-K wave groups + LDS dbuf pipeline ----
// 1024 blocks x 512 threads. wid = qs(0..3) | g<<2. Group g handles chunks
// 2i+g; groups have private dbuf tiles; block barrier drives both pipelines.
__global__ __launch_bounds__(512, 4) void k_attn(
    const f16* __restrict__ q, const f16* __restrict__ kmat,
    const f16* __restrict__ vt, const int* __restrict__ mlab,
    f16* __restrict__ ao)
{
    __shared__ f16 Ks[2][2][64 * 64];       // [group][buf]
    __shared__ f16 Vs[2][2][64 * 64];

    int bid = blockIdx.x;
    int bh = (bid & 7) + 8 * (bid >> 7);    // all 16 q-blocks of a bh on one XCD
    int qb = (bid >> 3) & 15;
    int b = bh >> 3, hh = bh & 7;
    int tid = threadIdx.x, wid = tid >> 6, lane = tid & 63;
    int qs = wid & 3, g = wid >> 2;
    int l15 = lane & 15, l4 = lane >> 4;
    int qbase = qb * 64;
    size_t bhs = (size_t)bh;

    if (mlab[b * 4 + (qb >> 2)] == 0) return;   // rows filled by k_gemm_out bias path

    unsigned long long chpack = 0; int nch = 0; // nch is a multiple of 4
#pragma unroll
    for (int s = 0; s < 4; ++s)
        if (mlab[b * 4 + s] != 0) {
#pragma unroll
            for (int j = 0; j < 4; ++j) {
                chpack |= (unsigned long long)(4 * s + j) << (4 * nch);
                ++nch;
            }
        }
    int niter = nch >> 1;                   // chunks per group

    f16x8 qf[2];
#pragma unroll
    for (int kk = 0; kk < 2; ++kk) {
        qf[kk] = *(const f16x8*)&q[(bhs * 1024 + qbase + qs * 16 + l15) * 64 + kk * 32 + l4 * 8];
#pragma unroll
        for (int j = 0; j < 8; ++j) qf[kk][j] = qf[kk][j] * (f16)0.125;
    }

    // group-local staging geometry (256 threads cover 512 16B slots)
    int gtid = tid & 255;
    int gw = wid & 3;
    int srow0 = gtid >> 3;
    int sc0 = ((gtid & 7) ^ (srow0 & 7)) << 3;
    int srow1 = (gtid + 256) >> 3;
    int sc1 = (((gtid + 256) & 7) ^ (srow1 & 7)) << 3;
    int lb0 = (gw * 64) * 8;
    int lb1 = (gw * 64 + 256) * 8;

#define STAGE(bi, t0)                                                                   \
    do {                                                                                \
        GLD16(&kmat[(bhs * 1024 + (t0) + srow0) * 64 + sc0], &Ks[g][bi][lb0]);          \
        GLD16(&kmat[(bhs * 1024 + (t0) + srow1) * 64 + sc1], &Ks[g][bi][lb1]);          \
        GLD16(&vt[(bhs * 64 + srow0) * 1024 + (t0) + sc0],   &Vs[g][bi][lb0]);          \
        GLD16(&vt[(bhs * 64 + srow1) * 1024 + (t0) + sc1],   &Vs[g][bi][lb1]);          \
    } while (0)

    float mrun = -1e30f, lrun = 0.f;
    f32x4 o[4] = {};
    int kxor = (l15 & 7) << 3;
    int srcA = l15 + ((l4 & 1) * 2) * 16;
    int srcB = srcA + 16;
    int sel = l4 >> 1;

    STAGE(0, (int)((chpack >> (4 * g)) & 15) << 6);   // group g's chunk 0 is global chunk g

    for (int i = 0; i < niter; ++i) {
        int bi = i & 1;
        __syncthreads();                    // buf bi ready; bi^1 free to overwrite
        if (i + 1 < niter) {                // prefetch next group-chunk under compute
            int cn = 2 * (i + 1) + g;
            int t0n = (int)((chpack >> (4 * cn)) & 15) << 6;
            STAGE(bi ^ 1, t0n);
        }

        // QK^T swapped: st[n] = S^T, k = n*16 + l4*4 + r, q-col = l15
        f32x4 st[4] = {};
        __builtin_amdgcn_s_setprio(1);
#pragma unroll
        for (int kk = 0; kk < 2; ++kk)
#pragma unroll
            for (int n = 0; n < 4; ++n) {
                f16x8 ka = *(const f16x8*)&Ks[g][bi][(n * 16 + l15) * 64 + ((kk * 32 + l4 * 8) ^ kxor)];
                st[n] = mfma16(ka, qf[kk], st[n]);
            }
        __builtin_amdgcn_s_setprio(0);

        // lane-local online softmax over this lane's 16 k-values
        f32x4 m4 = st[0];
#pragma unroll
        for (int n = 1; n < 4; ++n)
#pragma unroll
            for (int r = 0; r < 4; ++r) m4[r] = fmaxf(m4[r], st[n][r]);
        float mx = fmaxf(fmaxf(m4[0], m4[1]), fmaxf(m4[2], m4[3]));
        mx = fmaxf(mx, __shfl_xor(mx, 16));
        mx = fmaxf(mx, __shfl_xor(mx, 32));
        float mnew = fmaxf(mrun, mx);
        float alpha = __expf(mrun - mnew);
        mrun = mnew;
        float rs = 0.f;
        union PK { f16 h[4]; long long ll; } pk[4];
#pragma unroll
        for (int n = 0; n < 4; ++n)
#pragma unroll
            for (int r = 0; r < 4; ++r) {
                float p = __expf(st[n][r] - mnew);
                rs += p;
                pk[n].h[r] = (f16)p;
            }
        rs += __shfl_xor(rs, 16);
        rs += __shfl_xor(rs, 32);
        lrun = lrun * alpha + rs;
#pragma unroll
        for (int nd = 0; nd < 4; ++nd) o[nd] *= alpha;

        // P redistribution within 4-lane groups + PV
#pragma unroll
        for (int ks = 0; ks < 2; ++ks) {
            long long A0 = __shfl(pk[ks * 2].ll,     srcA);
            long long A1 = __shfl(pk[ks * 2 + 1].ll, srcA);
            long long B0 = __shfl(pk[ks * 2].ll,     srcB);
            long long B1 = __shfl(pk[ks * 2 + 1].ll, srcB);
            union PB { long long ll[2]; f16x8 v; } pb;
            pb.ll[0] = sel ? A1 : A0;
            pb.ll[1] = sel ? B1 : B0;
            __builtin_amdgcn_s_setprio(1);
#pragma unroll
            for (int nd = 0; nd < 4; ++nd) {
                f16x8 va = *(const f16x8*)&Vs[g][bi][(nd * 16 + l15) * 64 + ((ks * 32 + l4 * 8) ^ kxor)];
                o[nd] = mfma16(va, pb.v, o[nd]);
            }
            __builtin_amdgcn_s_setprio(0);
        }
    }
#undef STAGE

    // ---- 2-way split-K merge (aliases group-0 LDS, all compute done) ----
    float* mg  = (float*)&Ks[0][0][0];      // 4*64*16 f32 = 16KB (o partials, group 1)
    float* mml = (float*)&Vs[0][0][0];      // 128 f32 (m, l of group 1)
    __syncthreads();
    if (g == 1) {
        if (l4 == 0) { mml[qs * 16 + l15] = mrun; mml[64 + qs * 16 + l15] = lrun; }
#pragma unroll
        for (int nd = 0; nd < 4; ++nd)
#pragma unroll
            for (int r = 0; r < 4; ++r)
                mg[(qs * 64 + nd * 16 + l4 * 4 + r) * 16 + l15] = o[nd][r];
    }
    __syncthreads();
    if (g == 0) {
        float m1 = mml[qs * 16 + l15], l1 = mml[64 + qs * 16 + l15];
        float mst = fmaxf(mrun, m1);
        float e0 = __expf(mrun - mst), e1 = __expf(m1 - mst);
        float inv = 1.f / (lrun * e0 + l1 * e1);
        int qrow = qbase + qs * 16 + l15;
#pragma unroll
        for (int nd = 0; nd < 4; ++nd) {
            union { f16 h[4]; long long ll; } w;
#pragma unroll
            for (int r = 0; r < 4; ++r)
                w.h[r] = (f16)((o[nd][r] * e0 + mg[(qs * 64 + nd * 16 + l4 * 4 + r) * 16 + l15] * e1) * inv);
            *(long long*)&ao[(size_t)(b * 1024 + qrow) * 512 + hh * 64 + nd * 16 + l4 * 4] = w.ll;
        }
    }
}

// ---- out GEMM: 64x128 tile, LDS dbuf, single barrier/K-step, swizzled ----
__global__ __launch_bounds__(256, 3) void k_gemm_out(
    const f16* __restrict__ A, const f16* __restrict__ Bt, const int* __restrict__ mlab,
    const float* __restrict__ bias, float* __restrict__ out)
{
    __shared__ f16 As[2][64 * 64];
    __shared__ f16 Bs[2][128 * 64];
    int tid = threadIdx.x, wid = tid >> 6, lane = tid & 63;
    int wm = wid >> 1, wn = wid & 1;
    int l15 = lane & 15, l4 = lane >> 4;
    int rowBase = blockIdx.y * 64;
    int colBase = blockIdx.x * 128;
    if (mlab[(rowBase >> 10) * 4 + ((rowBase & 1023) >> 8)] == 0) {
        for (int i = tid; i < 64 * 128; i += 256)
            out[(size_t)(rowBase + (i >> 7)) * 512 + colBase + (i & 127)] = bias[colBase + (i & 127)];
        return;
    }

    int srow = lane >> 3;
    int scolz = ((lane & 7) ^ srow) << 3;
    int kxor = (l15 & 7) << 3;

#define STG(bi, kt)                                                                         \
    do {                                                                                    \
        _Pragma("unroll") for (int i_ = 0; i_ < 2; ++i_) {                                  \
            int rg = (wid * 2 + i_) * 8;                                                    \
            GLD16(&A[(size_t)(rowBase + rg + srow) * 512 + (kt) + scolz], &As[bi][rg * 64]);\
        }                                                                                   \
        _Pragma("unroll") for (int i_ = 0; i_ < 4; ++i_) {                                  \
            int rg = (wid * 4 + i_) * 8;                                                    \
            GLD16(&Bt[(size_t)(colBase + rg + srow) * 512 + (kt) + scolz], &Bs[bi][rg * 64]);\
        }                                                                                   \
    } while (0)

    f32x4 acc[2][4] = {};
    STG(0, 0);
    for (int ki = 0; ki < 8; ++ki) {
        int bi = ki & 1;
        __syncthreads();
        if (ki < 7) STG(bi ^ 1, (ki + 1) * 64);
#pragma unroll
        for (int kk = 0; kk < 2; ++kk) {
            f16x8 af[2], bf[4];
#pragma unroll
            for (int m = 0; m < 2; ++m)
                af[m] = *(const f16x8*)&As[bi][(wm * 32 + m * 16 + l15) * 64 + ((kk * 32 + l4 * 8) ^ kxor)];
#pragma unroll
            for (int n = 0; n < 4; ++n)
                bf[n] = *(const f16x8*)&Bs[bi][(wn * 64 + n * 16 + l15) * 64 + ((kk * 32 + l4 * 8) ^ kxor)];
#pragma unroll
            for (int m = 0; m < 2; ++m)
#pragma unroll
                for (int n = 0; n < 4; ++n)
                    acc[m][n] = mfma16(af[m], bf[n], acc[m][n]);
        }
    }
#undef STG
#pragma unroll
    for (int m = 0; m < 2; ++m)
#pragma unroll
        for (int n = 0; n < 4; ++n)
#pragma unroll
            for (int r = 0; r < 4; ++r) {
                int row = rowBase + wm * 32 + m * 16 + l4 * 4 + r;
                int col = colBase + wn * 64 + n * 16 + l15;
                out[(size_t)row * 512 + col] = acc[m][n][r] + bias[col];
            }
}

extern "C" void kernel_launch(void* const* d_in, const int* in_sizes, int n_in,
                              void* d_out, int out_size, void* d_ws, size_t ws_size,
                              hipStream_t stream) {
    const float* x     = (const float*)d_in[0];
    const int*   mlab  = (const int*)d_in[1];
    const float* gamma = (const float*)d_in[2];
    const float* beta  = (const float*)d_in[3];
    const float* wqkv  = (const float*)d_in[4];
    const float* wout  = (const float*)d_in[5];
    const float* bout  = (const float*)d_in[6];
    float* out = (float*)d_out;

    f16* h     = (f16*)d_ws;                 // 8192*512
    f16* wqkvT = h + 8192 * 512;             // 1536*512
    f16* woutT = wqkvT + 1536 * 512;         // 512*512
    f16* q     = woutT + 512 * 512;          // [B*H][1024][64]
    f16* kmat  = q + 4 * 1024 * 1024;
    f16* vt    = kmat + 4 * 1024 * 1024;     // [B*H][64][1024]
    f16* ao    = h;                          // h dead after QKV GEMM -> reuse

    k_prep<<<2304, 256, 0, stream>>>(x, gamma, beta, mlab, wqkv, wout, h, wqkvT, woutT);
    k_gemm_qkv<<<dim3(12, 128), 256, 0, stream>>>(h, wqkvT, mlab, q, kmat, vt);
    k_attn<<<1024, 512, 0, stream>>>(q, kmat, vt, mlab, ao);
    k_gemm_out<<<dim3(4, 128), 256, 0, stream>>>(ao, woutT, mlab, bout, out);
}